// Round 1
// baseline (6915.915 us; speedup 1.0000x reference)
//
#include <hip/hip_runtime.h>
#include <math.h>

#define BSZ 256
#define TIN 128
#define TOUT 64
#define ND 128
#define HID 512
#define PROJD 256

__global__ __launch_bounds__(256)
void zero_kernel(float* __restrict__ p, int n) {
    int i = blockIdx.x * 256 + threadIdx.x;
    if (i < n) p[i] = 0.f;
}

// ---------------- fused GRU step ----------------
// grid: (16 j-tiles of 32, 16 b-tiles of 16), 256 threads.
// Each thread: j-col = tid&31 (within tile), owns 2 batch rows (bq = tid>>5),
// accumulates r,z (merged x/h parts) and i_n, h_n separately.
__global__ __launch_bounds__(256)
void gru_step_kernel(const float* __restrict__ x, int x_stride,
                     const float* __restrict__ h_in,
                     float* __restrict__ h_out,
                     const float* __restrict__ Wi,   // [3*HID][ND]
                     const float* __restrict__ Wh,   // [3*HID][HID]
                     const float* __restrict__ bi,
                     const float* __restrict__ bh)
{
    __shared__ float U[16][648];    // cols [0,512): h, [512,640): x  (stride 648, 16B-aligned)
    __shared__ float Wt[96][68];    // 96 gate-rows x 64 K-cols per K-slice

    const int tid = threadIdx.x;
    const int jb  = blockIdx.x * 32;
    const int bb  = blockIdx.y * 16;

    // stage h tile: 16 x 512 floats = 2048 float4, 8 per thread
    #pragma unroll
    for (int i = 0; i < 8; ++i) {
        int lin = tid + i * 256;
        int r = lin >> 7;             // 128 f4 per row
        int c = (lin & 127) << 2;
        float4 v = *(const float4*)(h_in + (bb + r) * HID + c);
        *(float4*)&U[r][c] = v;
    }
    // stage x tile: 16 x 128 floats = 512 float4, 2 per thread
    #pragma unroll
    for (int i = 0; i < 2; ++i) {
        int lin = tid + i * 256;
        int r = lin >> 5;             // 32 f4 per row
        int c = (lin & 31) << 2;
        float4 v = *(const float4*)(x + (bb + r) * x_stride + c);
        *(float4*)&U[r][HID + c] = v;
    }

    const int jl = tid & 31;
    const int bq = tid >> 5;          // 0..7 -> batch rows {2bq, 2bq+1}

    float racc[2] = {0.f, 0.f};
    float zacc[2] = {0.f, 0.f};
    float nh[2]   = {0.f, 0.f};
    float ni[2]   = {0.f, 0.f};

    // ---- phase 1: K in [0,512) against Wh (accumulates h_r, h_z, h_n) ----
    for (int kt = 0; kt < 8; ++kt) {
        const int k0 = kt * 64;
        __syncthreads();
        #pragma unroll
        for (int i = 0; i < 6; ++i) {
            int lin = tid + i * 256;      // 96 rows x 16 f4
            int r = lin >> 4;
            int c = (lin & 15) << 2;
            int g = r >> 5, jr = r & 31;
            float4 v = *(const float4*)(Wh + (g * HID + jb + jr) * HID + k0 + c);
            *(float4*)&Wt[r][c] = v;
        }
        __syncthreads();
        #pragma unroll
        for (int kk = 0; kk < 64; kk += 4) {
            float4 wr = *(const float4*)&Wt[jl][kk];
            float4 wz = *(const float4*)&Wt[32 + jl][kk];
            float4 wn = *(const float4*)&Wt[64 + jl][kk];
            #pragma unroll
            for (int b2 = 0; b2 < 2; ++b2) {
                float4 hv = *(const float4*)&U[bq * 2 + b2][k0 + kk];
                racc[b2] += hv.x * wr.x + hv.y * wr.y + hv.z * wr.z + hv.w * wr.w;
                zacc[b2] += hv.x * wz.x + hv.y * wz.y + hv.z * wz.z + hv.w * wz.w;
                nh[b2]   += hv.x * wn.x + hv.y * wn.y + hv.z * wn.z + hv.w * wn.w;
            }
        }
    }

    // ---- phase 2: K in [0,128) against Wi (accumulates i_r, i_z, i_n) ----
    for (int kt = 0; kt < 2; ++kt) {
        const int k0 = kt * 64;
        __syncthreads();
        #pragma unroll
        for (int i = 0; i < 6; ++i) {
            int lin = tid + i * 256;
            int r = lin >> 4;
            int c = (lin & 15) << 2;
            int g = r >> 5, jr = r & 31;
            float4 v = *(const float4*)(Wi + (g * HID + jb + jr) * ND + k0 + c);
            *(float4*)&Wt[r][c] = v;
        }
        __syncthreads();
        #pragma unroll
        for (int kk = 0; kk < 64; kk += 4) {
            float4 wr = *(const float4*)&Wt[jl][kk];
            float4 wz = *(const float4*)&Wt[32 + jl][kk];
            float4 wn = *(const float4*)&Wt[64 + jl][kk];
            #pragma unroll
            for (int b2 = 0; b2 < 2; ++b2) {
                float4 hv = *(const float4*)&U[bq * 2 + b2][HID + k0 + kk];
                racc[b2] += hv.x * wr.x + hv.y * wr.y + hv.z * wr.z + hv.w * wr.w;
                zacc[b2] += hv.x * wz.x + hv.y * wz.y + hv.z * wz.z + hv.w * wz.w;
                ni[b2]   += hv.x * wn.x + hv.y * wn.y + hv.z * wn.z + hv.w * wn.w;
            }
        }
    }

    // ---- gates + update ----
    const int j = jb + jl;
    const float br  = bi[j] + bh[j];
    const float bz  = bi[HID + j] + bh[HID + j];
    const float bni = bi[2 * HID + j];
    const float bnh = bh[2 * HID + j];

    #pragma unroll
    for (int b2 = 0; b2 < 2; ++b2) {
        int b = bb + bq * 2 + b2;
        float rg = 1.f / (1.f + expf(-(racc[b2] + br)));
        float zg = 1.f / (1.f + expf(-(zacc[b2] + bz)));
        float ng = tanhf(ni[b2] + bni + rg * (nh[b2] + bnh));
        float ho = U[bq * 2 + b2][j];   // previous h, still resident in LDS
        h_out[b * HID + j] = (1.f - zg) * ng + zg * ho;
    }
}

// ---------------- decoder projection: proj = relu(h @ Wp.T + bp) ----------------
// grid: (8 p-tiles of 32, 16 b-tiles of 16), 256 threads
__global__ __launch_bounds__(256)
void proj_kernel(const float* __restrict__ h,
                 const float* __restrict__ Wp,    // [PROJD][HID]
                 const float* __restrict__ bp,
                 float* __restrict__ pr)          // [BSZ][PROJD]
{
    __shared__ float Hs[16][520];
    __shared__ float Wt[32][68];
    const int tid = threadIdx.x;
    const int pb  = blockIdx.x * 32;
    const int bb  = blockIdx.y * 16;

    #pragma unroll
    for (int i = 0; i < 8; ++i) {
        int lin = tid + i * 256;
        int r = lin >> 7, c = (lin & 127) << 2;
        *(float4*)&Hs[r][c] = *(const float4*)(h + (bb + r) * HID + c);
    }
    const int pl = tid & 31, bq = tid >> 5;
    float a0 = 0.f, a1 = 0.f;
    for (int kt = 0; kt < 8; ++kt) {
        const int k0 = kt * 64;
        __syncthreads();
        #pragma unroll
        for (int i = 0; i < 2; ++i) {
            int lin = tid + i * 256;        // 32 x 16 f4
            int r = lin >> 4, c = (lin & 15) << 2;
            *(float4*)&Wt[r][c] = *(const float4*)(Wp + (pb + r) * HID + k0 + c);
        }
        __syncthreads();
        #pragma unroll
        for (int kk = 0; kk < 64; kk += 4) {
            float4 w  = *(const float4*)&Wt[pl][kk];
            float4 u0 = *(const float4*)&Hs[bq * 2][k0 + kk];
            float4 u1 = *(const float4*)&Hs[bq * 2 + 1][k0 + kk];
            a0 += u0.x * w.x + u0.y * w.y + u0.z * w.z + u0.w * w.w;
            a1 += u1.x * w.x + u1.y * w.y + u1.z * w.z + u1.w * w.w;
        }
    }
    const float bpv = bp[pb + pl];
    const int b = bb + bq * 2;
    pr[b * PROJD + pb + pl]       = fmaxf(a0 + bpv, 0.f);
    pr[(b + 1) * PROJD + pb + pl] = fmaxf(a1 + bpv, 0.f);
}

// ---------------- decoder output: out = proj @ Wo.T + bo ----------------
// grid: (4 o-tiles of 32, 16 b-tiles of 16), 256 threads
__global__ __launch_bounds__(256)
void out_kernel(const float* __restrict__ pr,
                const float* __restrict__ Wo,    // [ND][PROJD]
                const float* __restrict__ bo,
                float* __restrict__ outp)        // base = d_out + t*ND, row stride TOUT*ND
{
    __shared__ float Ps[16][264];
    __shared__ float Wt[32][68];
    const int tid = threadIdx.x;
    const int ob  = blockIdx.x * 32;
    const int bb  = blockIdx.y * 16;

    #pragma unroll
    for (int i = 0; i < 4; ++i) {
        int lin = tid + i * 256;            // 16 x 64 f4
        int r = lin >> 6, c = (lin & 63) << 2;
        *(float4*)&Ps[r][c] = *(const float4*)(pr + (bb + r) * PROJD + c);
    }
    const int ol = tid & 31, bq = tid >> 5;
    float a0 = 0.f, a1 = 0.f;
    for (int kt = 0; kt < 4; ++kt) {
        const int k0 = kt * 64;
        __syncthreads();
        #pragma unroll
        for (int i = 0; i < 2; ++i) {
            int lin = tid + i * 256;
            int r = lin >> 4, c = (lin & 15) << 2;
            *(float4*)&Wt[r][c] = *(const float4*)(Wo + (ob + r) * PROJD + k0 + c);
        }
        __syncthreads();
        #pragma unroll
        for (int kk = 0; kk < 64; kk += 4) {
            float4 w  = *(const float4*)&Wt[ol][kk];
            float4 u0 = *(const float4*)&Ps[bq * 2][k0 + kk];
            float4 u1 = *(const float4*)&Ps[bq * 2 + 1][k0 + kk];
            a0 += u0.x * w.x + u0.y * w.y + u0.z * w.z + u0.w * w.w;
            a1 += u1.x * w.x + u1.y * w.y + u1.z * w.z + u1.w * w.w;
        }
    }
    const float bov = bo[ob + ol];
    const int b = bb + bq * 2;
    outp[b * (TOUT * ND) + ob + ol]       = a0 + bov;
    outp[(b + 1) * (TOUT * ND) + ob + ol] = a1 + bov;
}

extern "C" void kernel_launch(void* const* d_in, const int* in_sizes, int n_in,
                              void* d_out, int out_size, void* d_ws, size_t ws_size,
                              hipStream_t stream)
{
    (void)in_sizes; (void)n_in; (void)out_size; (void)ws_size;

    const float* X      = (const float*)d_in[0];
    const float* enc_Wi = (const float*)d_in[1];
    const float* enc_Wh = (const float*)d_in[2];
    const float* enc_bi = (const float*)d_in[3];
    const float* enc_bh = (const float*)d_in[4];
    const float* dec_Wi = (const float*)d_in[5];
    const float* dec_Wh = (const float*)d_in[6];
    const float* dec_bi = (const float*)d_in[7];
    const float* dec_bh = (const float*)d_in[8];
    const float* Wp     = (const float*)d_in[9];
    const float* bp     = (const float*)d_in[10];
    const float* Wo     = (const float*)d_in[11];
    const float* bo     = (const float*)d_in[12];
    float* out = (float*)d_out;

    float* hA = (float*)d_ws;                 // [BSZ][HID]
    float* hB = hA + BSZ * HID;               // [BSZ][HID]
    float* pr = hB + BSZ * HID;               // [BSZ][PROJD]

    zero_kernel<<<dim3((BSZ * HID) / 256), 256, 0, stream>>>(hA, BSZ * HID);

    dim3 gGRU(16, 16);
    float* hc = hA;
    float* hn = hB;

    // encoder: 128 steps over X[:, t, :]
    for (int t = 0; t < TIN; ++t) {
        gru_step_kernel<<<gGRU, 256, 0, stream>>>(X + t * ND, TIN * ND, hc, hn,
                                                  enc_Wi, enc_Wh, enc_bi, enc_bh);
        float* tmp = hc; hc = hn; hn = tmp;
    }

    // decoder: 64 autoregressive steps
    for (int t = 0; t < TOUT; ++t) {
        const float* xp; int xs;
        if (t == 0) { xp = X + (TIN - 1) * ND; xs = TIN * ND; }
        else        { xp = out + (t - 1) * ND; xs = TOUT * ND; }
        gru_step_kernel<<<gGRU, 256, 0, stream>>>(xp, xs, hc, hn,
                                                  dec_Wi, dec_Wh, dec_bi, dec_bh);
        float* tmp = hc; hc = hn; hn = tmp;
        proj_kernel<<<dim3(8, 16), 256, 0, stream>>>(hc, Wp, bp, pr);
        out_kernel<<<dim3(4, 16), 256, 0, stream>>>(pr, Wo, bo, out + t * ND);
    }
}

// Round 2
// 2658.193 us; speedup vs baseline: 2.6017x; 2.6017x over previous
//
#include <hip/hip_runtime.h>
#include <math.h>

#define TIN   128
#define TOUT  64
#define ND    128
#define HID   512
#define PROJD 256
#define BSZ   256

using f32x4 = __attribute__((ext_vector_type(4))) float;
using s16x8 = __attribute__((ext_vector_type(8))) short;

__device__ __forceinline__ unsigned short f2bf(float x) {
    unsigned int u = __builtin_bit_cast(unsigned int, x);
    u += 0x7fffu + ((u >> 16) & 1u);          // RNE (values finite)
    return (unsigned short)(u >> 16);
}
__device__ __forceinline__ float bf2f(unsigned short b) {
    unsigned int u = ((unsigned int)b) << 16;
    return __builtin_bit_cast(float, u);
}
__device__ __forceinline__ f32x4 mfma16(s16x8 a, s16x8 b, f32x4 c) {
    return __builtin_amdgcn_mfma_f32_16x16x32_bf16(a, b, c, 0, 0, 0);
}

// ---------------- one-time weight packing ----------------
// B-frag layout for W set with gates: [jf16][kb][g][hl][lane][8] ushort
// frag elem i of lane l = W[g*HID + jf16*16 + (l&15)][kb*32 + (l>>4)*8 + i]
__global__ __launch_bounds__(256)
void pack_gru_w(const float* __restrict__ Wh, const float* __restrict__ Wi,
                unsigned short* __restrict__ dst)
{
    int idx  = blockIdx.x * 256 + threadIdx.x;       // 32*20*3*64 = 122880
    int lane = idx & 63;
    int t    = idx >> 6;
    int g    = t % 3;  t /= 3;
    int kb   = t % 20; t /= 20;
    int jf16 = t;
    if (jf16 >= 32) return;

    int row = g * HID + jf16 * 16 + (lane & 15);
    int kk  = kb * 32 + (lane >> 4) * 8;
    float v[8];
    if (kb < 16) {
        const float* s = Wh + (size_t)row * HID + kk;
        #pragma unroll
        for (int i = 0; i < 8; ++i) v[i] = s[i];
    } else {
        const float* s = Wi + (size_t)row * ND + (kk - HID);
        #pragma unroll
        for (int i = 0; i < 8; ++i) v[i] = s[i];
    }
    unsigned short hi[8], lo[8];
    #pragma unroll
    for (int i = 0; i < 8; ++i) {
        hi[i] = f2bf(v[i]);
        lo[i] = f2bf(v[i] - bf2f(hi[i]));
    }
    size_t base = ((((size_t)(jf16 * 20 + kb) * 3 + g) * 2 + 0) * 64 + lane) * 8;
    #pragma unroll
    for (int i = 0; i < 8; ++i) { dst[base + i] = hi[i]; dst[base + 512 + i] = lo[i]; }
}

// plain weight (no gates): [jf16][kb][hl][lane][8]
__global__ __launch_bounds__(256)
void pack_plain_w(const float* __restrict__ W, int K, int NF, int KB,
                  unsigned short* __restrict__ dst)
{
    int idx  = blockIdx.x * 256 + threadIdx.x;
    int lane = idx & 63;
    int t    = idx >> 6;
    int kb   = t % KB;
    int jf16 = t / KB;
    if (jf16 >= NF) return;

    int row = jf16 * 16 + (lane & 15);
    int kk  = kb * 32 + (lane >> 4) * 8;
    const float* s = W + (size_t)row * K + kk;
    size_t base = (((size_t)(jf16 * KB + kb) * 2 + 0) * 64 + lane) * 8;
    #pragma unroll
    for (int i = 0; i < 8; ++i) {
        float v = s[i];
        unsigned short hi = f2bf(v);
        dst[base + i]       = hi;
        dst[base + 512 + i] = f2bf(v - bf2f(hi));
    }
}

__global__ __launch_bounds__(256)
void prep_bias(const float* __restrict__ bi, const float* __restrict__ bh,
               float4* __restrict__ dst)
{
    int j = blockIdx.x * 256 + threadIdx.x;
    if (j >= HID) return;
    dst[j] = make_float4(bi[j] + bh[j],
                         bi[HID + j] + bh[HID + j],
                         bi[2 * HID + j],
                         bh[2 * HID + j]);
}

__global__ __launch_bounds__(256)
void zero_u32(unsigned int* __restrict__ p, int n) {
    int i = blockIdx.x * 256 + threadIdx.x;
    if (i < n) p[i] = 0u;
}

// ---------------- fused GRU step (MFMA, bf16 hi/lo split) ----------------
// grid (16 jt, 16 bt), 128 threads = 2 waves (wave = jf half of the 32-j tile).
// K = 640: kb 0-15 read h A-frags; kb 16-19 convert x from fp32 in-register.
// hA layout: [bt16][kb16][hl][lane][8] ushort.
__global__ __launch_bounds__(128)
void gru_mfma(const unsigned short* __restrict__ WB,   // [32][20][3][2][64][8]
              const float* __restrict__ xsrc, int xstride,
              const unsigned short* __restrict__ hA_in,
              const float* __restrict__ hf_in,
              float* __restrict__ hf_out,
              unsigned short* __restrict__ hA_out,
              const float4* __restrict__ bias4)
{
    const int lane = threadIdx.x & 63;
    const int wv   = threadIdx.x >> 6;       // 0/1
    const int jt   = blockIdx.x;             // 0..15
    const int bt   = blockIdx.y;             // 0..15
    const int jf16 = jt * 2 + wv;

    f32x4 acc[4][3];                          // gates r,z,n_h,n_x  x  3 splits
    #pragma unroll
    for (int g = 0; g < 4; ++g)
        #pragma unroll
        for (int s = 0; s < 3; ++s)
            acc[g][s] = (f32x4){0.f, 0.f, 0.f, 0.f};

    const unsigned short* hAb = hA_in + (size_t)bt * 16 * 2 * 64 * 8;
    const unsigned short* wbb = WB + (size_t)jf16 * 20 * 3 * 2 * 64 * 8;

    // ---- h part: kb 0..15 ----
    #pragma unroll 2
    for (int kb = 0; kb < 16; ++kb) {
        s16x8 ahi = *(const s16x8*)(hAb + ((size_t)(kb * 2 + 0) * 64 + lane) * 8);
        s16x8 alo = *(const s16x8*)(hAb + ((size_t)(kb * 2 + 1) * 64 + lane) * 8);
        const unsigned short* wk = wbb + (size_t)kb * 3 * 2 * 64 * 8;
        #pragma unroll
        for (int g = 0; g < 3; ++g) {
            s16x8 bhi = *(const s16x8*)(wk + ((size_t)(g * 2 + 0) * 64 + lane) * 8);
            s16x8 blo = *(const s16x8*)(wk + ((size_t)(g * 2 + 1) * 64 + lane) * 8);
            acc[g][0] = mfma16(ahi, bhi, acc[g][0]);
            acc[g][1] = mfma16(ahi, blo, acc[g][1]);
            acc[g][2] = mfma16(alo, bhi, acc[g][2]);
        }
    }

    // ---- x part: kb 16..19 (convert fp32 -> hi/lo in-register) ----
    #pragma unroll
    for (int kb = 16; kb < 20; ++kb) {
        const float* xs = xsrc + (size_t)(bt * 16 + (lane & 15)) * xstride
                               + (kb - 16) * 32 + (lane >> 4) * 8;
        float4 v0 = *(const float4*)xs;
        float4 v1 = *(const float4*)(xs + 4);
        float vv[8] = {v0.x, v0.y, v0.z, v0.w, v1.x, v1.y, v1.z, v1.w};
        s16x8 ahi, alo;
        #pragma unroll
        for (int i = 0; i < 8; ++i) {
            unsigned short h = f2bf(vv[i]);
            ahi[i] = (short)h;
            alo[i] = (short)f2bf(vv[i] - bf2f(h));
        }
        const unsigned short* wk = wbb + (size_t)kb * 3 * 2 * 64 * 8;
        #pragma unroll
        for (int g = 0; g < 3; ++g) {
            int ga = (g == 2) ? 3 : g;
            s16x8 bhi = *(const s16x8*)(wk + ((size_t)(g * 2 + 0) * 64 + lane) * 8);
            s16x8 blo = *(const s16x8*)(wk + ((size_t)(g * 2 + 1) * 64 + lane) * 8);
            acc[ga][0] = mfma16(ahi, bhi, acc[ga][0]);
            acc[ga][1] = mfma16(ahi, blo, acc[ga][1]);
            acc[ga][2] = mfma16(alo, bhi, acc[ga][2]);
        }
    }

    f32x4 racc = acc[0][0] + acc[0][1] + acc[0][2];
    f32x4 zacc = acc[1][0] + acc[1][1] + acc[1][2];
    f32x4 nhac = acc[2][0] + acc[2][1] + acc[2][2];
    f32x4 nxac = acc[3][0] + acc[3][1] + acc[3][2];

    // ---- gates + h update ----
    const int j = jf16 * 16 + (lane & 15);
    const float4 b4 = bias4[j];
    __shared__ float hs[16][33];

    #pragma unroll
    for (int i = 0; i < 4; ++i) {
        int b = bt * 16 + (lane >> 4) * 4 + i;
        float r  = 1.f / (1.f + expf(-(racc[i] + b4.x)));
        float z  = 1.f / (1.f + expf(-(zacc[i] + b4.y)));
        float n  = tanhf(nxac[i] + b4.z + r * (nhac[i] + b4.w));
        float ho = hf_in[(size_t)b * HID + j];
        float hv = (1.f - z) * n + z * ho;
        hf_out[(size_t)b * HID + j] = hv;
        hs[(lane >> 4) * 4 + i][wv * 16 + (lane & 15)] = hv;
    }
    __syncthreads();

    // write h A-frags for next step (this WG owns kb = jt)
    if (wv == 0) {
        unsigned short hi8[8], lo8[8];
        #pragma unroll
        for (int i = 0; i < 8; ++i) {
            float v = hs[lane & 15][(lane >> 4) * 8 + i];
            hi8[i] = f2bf(v);
            lo8[i] = f2bf(v - bf2f(hi8[i]));
        }
        unsigned short* d = hA_out + (((size_t)(bt * 16 + jt) * 2 + 0) * 64 + lane) * 8;
        #pragma unroll
        for (int i = 0; i < 8; ++i) { d[i] = hi8[i]; d[512 + i] = lo8[i]; }
    }
}

// ---------------- proj = relu(h @ Wp.T + bp), emits A-frags ----------------
__global__ __launch_bounds__(128)
void proj_mfma(const unsigned short* __restrict__ WB,   // [16][16][2][64][8]
               const unsigned short* __restrict__ hA,
               const float* __restrict__ bp,
               unsigned short* __restrict__ projA)       // [16][8][2][64][8]
{
    const int lane = threadIdx.x & 63;
    const int wv   = threadIdx.x >> 6;
    const int pt   = blockIdx.x;              // 0..7
    const int bt   = blockIdx.y;
    const int pf16 = pt * 2 + wv;

    f32x4 a0 = {0.f,0.f,0.f,0.f}, a1 = a0, a2 = a0;
    const unsigned short* hAb = hA + (size_t)bt * 16 * 2 * 64 * 8;
    const unsigned short* wbb = WB + (size_t)pf16 * 16 * 2 * 64 * 8;
    #pragma unroll 2
    for (int kb = 0; kb < 16; ++kb) {
        s16x8 ahi = *(const s16x8*)(hAb + ((size_t)(kb * 2 + 0) * 64 + lane) * 8);
        s16x8 alo = *(const s16x8*)(hAb + ((size_t)(kb * 2 + 1) * 64 + lane) * 8);
        s16x8 bhi = *(const s16x8*)(wbb + ((size_t)(kb * 2 + 0) * 64 + lane) * 8);
        s16x8 blo = *(const s16x8*)(wbb + ((size_t)(kb * 2 + 1) * 64 + lane) * 8);
        a0 = mfma16(ahi, bhi, a0);
        a1 = mfma16(ahi, blo, a1);
        a2 = mfma16(alo, bhi, a2);
    }
    f32x4 acc = a0 + a1 + a2;

    const int p = pf16 * 16 + (lane & 15);
    const float bpv = bp[p];
    __shared__ float hs[16][33];
    #pragma unroll
    for (int i = 0; i < 4; ++i)
        hs[(lane >> 4) * 4 + i][wv * 16 + (lane & 15)] = fmaxf(acc[i] + bpv, 0.f);
    __syncthreads();

    if (wv == 0) {
        unsigned short hi8[8], lo8[8];
        #pragma unroll
        for (int i = 0; i < 8; ++i) {
            float v = hs[lane & 15][(lane >> 4) * 8 + i];
            hi8[i] = f2bf(v);
            lo8[i] = f2bf(v - bf2f(hi8[i]));
        }
        unsigned short* d = projA + (((size_t)(bt * 8 + pt) * 2 + 0) * 64 + lane) * 8;
        #pragma unroll
        for (int i = 0; i < 8; ++i) { d[i] = hi8[i]; d[512 + i] = lo8[i]; }
    }
}

// ---------------- out = proj @ Wo.T + bo ----------------
__global__ __launch_bounds__(128)
void out_mfma(const unsigned short* __restrict__ WB,    // [8][8][2][64][8]
              const unsigned short* __restrict__ projA,
              const float* __restrict__ bo,
              float* __restrict__ outp)                  // d_out + t*ND
{
    const int lane = threadIdx.x & 63;
    const int wv   = threadIdx.x >> 6;
    const int ot   = blockIdx.x;               // 0..3
    const int bt   = blockIdx.y;
    const int of16 = ot * 2 + wv;

    f32x4 a0 = {0.f,0.f,0.f,0.f}, a1 = a0, a2 = a0;
    const unsigned short* pAb = projA + (size_t)bt * 8 * 2 * 64 * 8;
    const unsigned short* wbb = WB + (size_t)of16 * 8 * 2 * 64 * 8;
    #pragma unroll
    for (int kb = 0; kb < 8; ++kb) {
        s16x8 ahi = *(const s16x8*)(pAb + ((size_t)(kb * 2 + 0) * 64 + lane) * 8);
        s16x8 alo = *(const s16x8*)(pAb + ((size_t)(kb * 2 + 1) * 64 + lane) * 8);
        s16x8 bhi = *(const s16x8*)(wbb + ((size_t)(kb * 2 + 0) * 64 + lane) * 8);
        s16x8 blo = *(const s16x8*)(wbb + ((size_t)(kb * 2 + 1) * 64 + lane) * 8);
        a0 = mfma16(ahi, bhi, a0);
        a1 = mfma16(ahi, blo, a1);
        a2 = mfma16(alo, bhi, a2);
    }
    f32x4 acc = a0 + a1 + a2;

    const int o = of16 * 16 + (lane & 15);
    const float bov = bo[o];
    #pragma unroll
    for (int i = 0; i < 4; ++i) {
        int b = bt * 16 + (lane >> 4) * 4 + i;
        outp[(size_t)b * (TOUT * ND) + o] = acc[i] + bov;
    }
}

extern "C" void kernel_launch(void* const* d_in, const int* in_sizes, int n_in,
                              void* d_out, int out_size, void* d_ws, size_t ws_size,
                              hipStream_t stream)
{
    (void)in_sizes; (void)n_in; (void)out_size; (void)ws_size;

    const float* X      = (const float*)d_in[0];
    const float* enc_Wi = (const float*)d_in[1];
    const float* enc_Wh = (const float*)d_in[2];
    const float* enc_bi = (const float*)d_in[3];
    const float* enc_bh = (const float*)d_in[4];
    const float* dec_Wi = (const float*)d_in[5];
    const float* dec_Wh = (const float*)d_in[6];
    const float* dec_bi = (const float*)d_in[7];
    const float* dec_bh = (const float*)d_in[8];
    const float* Wp     = (const float*)d_in[9];
    const float* bp     = (const float*)d_in[10];
    const float* Wo     = (const float*)d_in[11];
    const float* bo     = (const float*)d_in[12];
    float* out = (float*)d_out;

    char* w = (char*)d_ws;
    size_t off = 0;
    auto alloc = [&](size_t bytes) { void* p = w + off; off += (bytes + 255) & ~(size_t)255; return p; };

    unsigned short* encB  = (unsigned short*)alloc(32u*20*3*2*64*8 * 2);   // 3.93 MB
    unsigned short* decB  = (unsigned short*)alloc(32u*20*3*2*64*8 * 2);
    unsigned short* WpB   = (unsigned short*)alloc(16u*16*2*64*8 * 2);     // 512 KB
    unsigned short* WoB   = (unsigned short*)alloc(8u*8*2*64*8 * 2);       // 128 KB
    float*          hf0   = (float*)alloc((size_t)BSZ*HID*4);
    float*          hf1   = (float*)alloc((size_t)BSZ*HID*4);
    unsigned short* hA0   = (unsigned short*)alloc(16u*16*2*64*8 * 2);     // 512 KB
    unsigned short* hA1   = (unsigned short*)alloc(16u*16*2*64*8 * 2);
    unsigned short* projA = (unsigned short*)alloc(16u*8*2*64*8 * 2);      // 256 KB
    float4*         biasE = (float4*)alloc(HID * 16);
    float4*         biasD = (float4*)alloc(HID * 16);

    // one-time prep (runs every call; deterministic)
    pack_gru_w<<<480, 256, 0, stream>>>(enc_Wh, enc_Wi, encB);
    pack_gru_w<<<480, 256, 0, stream>>>(dec_Wh, dec_Wi, decB);
    pack_plain_w<<<64, 256, 0, stream>>>(Wp, HID, 16, 16, WpB);
    pack_plain_w<<<16, 256, 0, stream>>>(Wo, PROJD, 8, 8, WoB);
    prep_bias<<<2, 256, 0, stream>>>(enc_bi, enc_bh, biasE);
    prep_bias<<<2, 256, 0, stream>>>(dec_bi, dec_bh, biasD);
    zero_u32<<<512, 256, 0, stream>>>((unsigned int*)hf0, BSZ * HID);
    zero_u32<<<512, 256, 0, stream>>>((unsigned int*)hA0, 16 * 16 * 2 * 64 * 8 / 2);

    float*          hf[2] = {hf0, hf1};
    unsigned short* hA[2] = {hA0, hA1};
    int cur = 0;
    dim3 gG(16, 16);

    // encoder
    for (int t = 0; t < TIN; ++t) {
        gru_mfma<<<gG, 128, 0, stream>>>(encB, X + (size_t)t * ND, TIN * ND,
                                         hA[cur], hf[cur], hf[cur ^ 1], hA[cur ^ 1], biasE);
        cur ^= 1;
    }
    // decoder
    for (int t = 0; t < TOUT; ++t) {
        const float* xs; int xstride;
        if (t == 0) { xs = X + (size_t)(TIN - 1) * ND; xstride = TIN * ND; }
        else        { xs = out + (size_t)(t - 1) * ND; xstride = TOUT * ND; }
        gru_mfma<<<gG, 128, 0, stream>>>(decB, xs, xstride,
                                         hA[cur], hf[cur], hf[cur ^ 1], hA[cur ^ 1], biasD);
        cur ^= 1;
        proj_mfma<<<dim3(8, 16), 128, 0, stream>>>(WpB, hA[cur], bp, projA);
        out_mfma<<<dim3(4, 16), 128, 0, stream>>>(WoB, projA, bo, out + (size_t)t * ND);
    }
}